// Round 14
// baseline (334.573 us; speedup 1.0000x reference)
//
#include <hip/hip_runtime.h>
#include <hip/hip_bf16.h>

#define NN 64
#define BATCH 512
#define SP 60
#define SG 180
#define SEX 10
#define CATD 80
#define NA 5
#define NR 7
#define OO 8
#define II 8

typedef unsigned long long u64;
typedef unsigned short u16;
typedef unsigned int u32;
typedef unsigned char u8;

// ---- workspace layout (float offsets) ----
#define OFF_Z     0
#define OFF_DZ    327680
#define OFF_HAS   655360
#define OFF_WIHF  688128
#define OFF_WHHF  698928
#define OFF_BIHF  709728
#define OFF_BHHF  709908
#define OFF_WIHB  710088
#define OFF_WHHB  720888
#define OFF_BIHB  731688
#define OFF_BHHB  731868
#define OFF_WF    732048
#define OFF_BF    736848
#define OFF_WB    736908
#define OFF_BB    741708
#define CONV_TOTAL 741768
#define OFF_RHOF  741776
#define OFF_RHOB  (OFF_RHOF + 1966080)
#define OFF_ALF   (OFF_RHOB + 1966080)
#define OFF_ALB   (OFF_ALF + 30720)
#define OUT_TOTAL 232448

typedef _Float16 f16;
typedef _Float16 half2_t __attribute__((ext_vector_type(2)));
typedef _Float16 f16x8 __attribute__((ext_vector_type(8)));
typedef float f32x4 __attribute__((ext_vector_type(4)));

__device__ __forceinline__ float us2f(u16 v){
  return __uint_as_float(((u32)v) << 16);
}
__device__ __forceinline__ u16 f2bf(float f){
  __hip_bfloat16 h = __float2bfloat16(f);
  return *reinterpret_cast<u16*>(&h);
}
__device__ __forceinline__ float rcp_(float x){ return __builtin_amdgcn_rcpf(x); }
__device__ __forceinline__ float sigm(float x){
  return rcp_(1.f + __expf(-x));
}
__device__ __forceinline__ float tanh_(float x){
  float e = __expf(2.f*fabsf(x));
  float t = 1.f - 2.f*rcp_(e + 1.f);
  return copysignf(t, x);
}
__device__ __forceinline__ u32 pack2(float a, float b){
  half2_t h; h[0] = (f16)a; h[1] = (f16)b;
  return __builtin_bit_cast(u32, h);
}
__device__ __forceinline__ float fdot2_(u32 a, u32 b, float c){
  return __builtin_amdgcn_fdot2(__builtin_bit_cast(half2_t, a),
                                __builtin_bit_cast(half2_t, b), c, false);
}
__device__ __forceinline__ f16x8 bc16(uint4 v){ return __builtin_bit_cast(f16x8, v); }
__device__ __forceinline__ f32x4 mfma16(f16x8 a, f16x8 b, f32x4 c){
  return __builtin_amdgcn_mfma_f32_16x16x32_f16(a, b, c, 0, 0, 0);
}

struct HP { uint4 q[8]; };
__device__ __forceinline__ u32 hpc(const HP& p, int k){
  const uint4& v = p.q[k>>2];
  switch(k&3){ case 0: return v.x; case 1: return v.y; case 2: return v.z; default: return v.w; }
}

// has is exactly {0,1}. f32 words: only 0x00000000 / 0x3F800000.
// bf16-pair words: 0x3F803F80 == (1.0,1.0) appears w.p. ~0.81 per pair.
__device__ __forceinline__ int detect_bf16(const u32* w){
  int f = 0;
  for (int i=0;i<256;i++) f |= (w[i] == 0x3F803F80u) ? 1 : 0;
  return f;
}

__global__ __launch_bounds__(256) void conv_in(
  const void* z, const void* dz, const void* has,
  const void* WihF, const void* WhhF, const void* bihF, const void* bhhF,
  const void* WihB, const void* WhhB, const void* bihB, const void* bhhB,
  const void* Wf_, const void* bf_, const void* Wb_, const void* bb_,
  float* ws)
{
  const int isbf = detect_bf16((const u32*)has);
  int idx = blockIdx.x*256 + threadIdx.x;
  if (idx >= CONV_TOTAL) return;
  const void* src; int loc;
  if      (idx < OFF_DZ  ){ src=z;    loc=idx-OFF_Z;    }
  else if (idx < OFF_HAS ){ src=dz;   loc=idx-OFF_DZ;   }
  else if (idx < OFF_WIHF){ src=has;  loc=idx-OFF_HAS;  }
  else if (idx < OFF_WHHF){ src=WihF; loc=idx-OFF_WIHF; }
  else if (idx < OFF_BIHF){ src=WhhF; loc=idx-OFF_WHHF; }
  else if (idx < OFF_BHHF){ src=bihF; loc=idx-OFF_BIHF; }
  else if (idx < OFF_WIHB){ src=bhhF; loc=idx-OFF_BHHF; }
  else if (idx < OFF_WHHB){ src=WihB; loc=idx-OFF_WIHB; }
  else if (idx < OFF_BIHB){ src=WhhB; loc=idx-OFF_WHHB; }
  else if (idx < OFF_BHHB){ src=bihB; loc=idx-OFF_BIHB; }
  else if (idx < OFF_WF  ){ src=bhhB; loc=idx-OFF_BHHB; }
  else if (idx < OFF_BF  ){ src=Wf_;  loc=idx-OFF_WF;   }
  else if (idx < OFF_WB  ){ src=bf_;  loc=idx-OFF_BF;   }
  else if (idx < OFF_BB  ){ src=Wb_;  loc=idx-OFF_WB;   }
  else                    { src=bb_;  loc=idx-OFF_BB;   }
  float v = isbf ? us2f(((const u16*)src)[loc]) : ((const float*)src)[loc];
  ws[idx] = v;
}

// Pipelined DAG-GRU, MFMA with in-register gates.
// Round-14: TWO waves per chain. Wave w owns gate-row tiles {2w,2w+1}
// (units 32w..32w+31): half the GEMMs, gates, and h-writes per wave, shared
// LDS state. 8 waves/CU (2/SIMD) instead of 4 — latency overlap at last.
// Phase 1 (rho) runs on wave0 only (no replication; wave1's wait overlaps
// other blocks' work on the SIMD).
__global__ __launch_bounds__(128, 1) void dir_kernel(const int* __restrict__ adj,
                                                     float* __restrict__ ws)
{
  const int tid = threadIdx.x;
  const int wv  = tid >> 6;         // wave 0/1
  const int u   = tid & 63;         // lane
  const int ml  = u & 15;           // MFMA col (consumer slot)
  const int q   = u >> 4;           // MFMA quad
  const int bid = blockIdx.x;
  const int bwd = bid >> 9;
  const int b   = bid & 511;

  const float* Wih  = ws + (bwd ? OFF_WIHB : OFF_WIHF);
  const float* Whh  = ws + (bwd ? OFF_WHHB : OFF_WHHF);
  const float* bih  = ws + (bwd ? OFF_BIHB : OFF_BIHF);
  const float* bhh  = ws + (bwd ? OFF_BHHB : OFF_BHHF);
  const float* Wcat = ws + (bwd ? OFF_WB   : OFF_WF);
  const float* bcat = ws + (bwd ? OFF_BB   : OFF_BF);
  const float* zc   = ws + OFF_Z;
  const float* dzc  = ws + OFF_DZ;
  const float* hasc = ws + OFF_HAS;
  float* rho   = ws + (bwd ? OFF_RHOB : OFF_RHOF);  // [64][512][60]
  float* alpha = ws + (bwd ? OFF_ALB  : OFF_ALF);   // [512][60]

  __shared__ uint4 sH4[65][9];        // h rows, 144B stride; half63=1.0 (bias ch)
  __shared__ uint4 sRhoPad[8];        // rho_t halves; half63=1.0
  __shared__ uint4 sRhoHist[8][8];    // tail rho history; half63=1.0
  __shared__ float sRhoOut[NN][SP];   // f32 rho staging (bulk global write)
  __shared__ u32 sZp[NN][5];
  __shared__ u32 sDZp[NN][5];
  __shared__ float sHas[NN];
  __shared__ u64 sRowM[NN];
  __shared__ u8 sConsL[NN][64];       // consumer lists (batch-independent)
  __shared__ int sConsCnt[NN];

  #define ROWB(I) ((char*)&sH4[(I)][0])
  const u32 BIASW = 0x3C000000u;      // halves {0, 1.0h}

  // ---- staging (128 threads) ----
  u64 rowm = 0;
  if (tid < NN){
    for (int j=0;j<64;j++) rowm |= ((u64)(adj[tid*64+j]!=0))<<j;
    sRowM[tid] = rowm;
    sHas[tid] = hasc[b*NN + tid];
  }
  for (int idx=tid; idx<65*9; idx+=128){
    uint4 v = {0,0,0,0};
    if (idx % 9 == 7) v.w = BIASW;           // half63 = 1.0
    ((uint4*)sH4)[idx] = v;
  }
  if (tid < 8){ uint4 v={0,0,0,0}; if (tid==7) v.w = BIASW; sRhoPad[tid]=v; }
  if (tid < 64){ uint4 v={0,0,0,0}; if ((tid&7)==7) v.w = BIASW; ((uint4*)sRhoHist)[tid]=v; }
  for (int idx=tid; idx<NN*5; idx+=128){
    int n2=idx/5, p2=idx%5;
    sZp [n2][p2] = pack2(zc [(size_t)b*NN*SEX + n2*SEX + 2*p2],
                         zc [(size_t)b*NN*SEX + n2*SEX + 2*p2+1]);
    sDZp[n2][p2] = pack2(dzc[(size_t)b*NN*SEX + n2*SEX + 2*p2],
                         dzc[(size_t)b*NN*SEX + n2*SEX + 2*p2+1]);
  }
  __syncthreads();
  if (tid < NN){
    u64 cm = 0;
    if (bwd) for (int i2=0;i2<64;i2++) cm |= ((sRowM[i2]>>tid)&1ULL)<<i2;
    u64 m = bwd ? cm : rowm;                // consumers of node tid
    int c = 0;
    while (m){ int i2 = (int)__builtin_ctzll(m); m &= m-1; sConsL[tid][c++] = (u8)i2; }
    sConsCnt[tid] = c;
  }

  // ---- A fragments: wave wv owns global m-tiles {2wv, 2wv+1} ----
  f16x8 Ar[2][4], Az[2][4], Anh[2][2], Ani[2][2];
  #pragma unroll
  for (int lmt=0; lmt<2; lmt++){
    const int gmt = 2*wv + lmt;
    const int R = 16*gmt + ml;
    const bool rok = (R < SP);
    #pragma unroll
    for (int kt=0; kt<4; kt++){
      f16x8 vr, vz;
      #pragma unroll
      for (int j=0;j<8;j++){
        const int K = 32*kt + 8*q + j;
        float wr=0.f, wz=0.f;
        if (rok){
          if (K < SP){ wr = Whh[R*SP+K]; wz = Whh[(60+R)*SP+K]; }
          else if (K >= 64 && K < 64+SP){ wr = Wih[R*SP+(K-64)]; wz = Wih[(60+R)*SP+(K-64)]; }
          else if (K == 127){ wr = bhh[R]+bih[R]; wz = bhh[60+R]+bih[60+R]; }
        }
        vr[j]=(f16)wr; vz[j]=(f16)wz;
      }
      Ar[lmt][kt]=vr; Az[lmt][kt]=vz;
    }
    #pragma unroll
    for (int kt=0; kt<2; kt++){
      f16x8 vn, vi;
      #pragma unroll
      for (int j=0;j<8;j++){
        const int K = 32*kt + 8*q + j;
        float wn=0.f, wi=0.f;
        if (rok){
          if (K < SP){ wn = Whh[(120+R)*SP+K]; wi = Wih[(120+R)*SP+K]; }
          else if (K == 63){ wn = bhh[120+R]; wi = bih[120+R]; }
        }
        vn[j]=(f16)wn; vi[j]=(f16)wi;
      }
      Anh[lmt][kt]=vn; Ani[lmt][kt]=vi;
    }
  }

  // rho weights (packed f16 pairs) + bias — wave0 only (phase-1 owner)
  u32 wc[40];
  float bct = 0.f;
  if (wv == 0){
    #pragma unroll
    for (int k=0;k<40;k++) wc[k] = pack2(Wcat[u*CATD + 2*k], Wcat[u*CATD + 2*k+1]);
    bct = bcat[u];
  }
  __syncthreads();   // lists + LDS init visible

  // gate pass: half-GEMMs + in-register gates + h half-row update
  auto gatepass = [&](f16x8 Bh0, f16x8 Bh1, f16x8 Br0, f16x8 Br1,
                      const f32x4* Gn, int ci, bool wr, float bl){
    f32x4 Dr[2], Dz[2], Dn[2];
    #pragma unroll
    for (int lmt=0;lmt<2;lmt++){
      f32x4 a={0,0,0,0};
      a = mfma16(Ar[lmt][0], Bh0, a); a = mfma16(Ar[lmt][1], Bh1, a);
      a = mfma16(Ar[lmt][2], Br0, a); a = mfma16(Ar[lmt][3], Br1, a);
      Dr[lmt] = a;
      f32x4 c2={0,0,0,0};
      c2 = mfma16(Az[lmt][0], Bh0, c2); c2 = mfma16(Az[lmt][1], Bh1, c2);
      c2 = mfma16(Az[lmt][2], Br0, c2); c2 = mfma16(Az[lmt][3], Br1, c2);
      Dz[lmt] = c2;
      f32x4 d={0,0,0,0};
      d = mfma16(Anh[lmt][0], Bh0, d); d = mfma16(Anh[lmt][1], Bh1, d);
      Dn[lmt] = d;
    }
    #pragma unroll
    for (int lmt=0;lmt<2;lmt++){
      const int gmt = 2*wv + lmt;
      char* rp = ROWB(ci) + 32*gmt + 8*q;
      uint2 h2 = *(uint2*)rp;
      half2_t ha = __builtin_bit_cast(half2_t, h2.x);
      half2_t hb = __builtin_bit_cast(half2_t, h2.y);
      float hold[4] = { (float)ha[0], (float)ha[1], (float)hb[0], (float)hb[1] };
      float hw[4];
      #pragma unroll
      for (int reg=0;reg<4;reg++){
        float r_ = sigm(Dr[lmt][reg]);
        float zg = sigm(Dz[lmt][reg]);
        float nv = tanh_(Gn[lmt][reg] + r_*Dn[lmt][reg]);
        float hn_ = (1.f - zg)*nv + zg*hold[reg];
        hw[reg] = (bl != 0.f) ? hn_ : hold[reg];   // bl is exactly 0 or 1
      }
      if (wr && !(gmt==3 && q==3)){
        uint2 o; o.x = pack2(hw[0],hw[1]); o.y = pack2(hw[2],hw[3]);
        *(uint2*)rp = o;
      }
    }
  };

  // ---- 64 pipelined steps ----
  int t = bwd ? 63 : 0;
  const int dt = bwd ? -1 : 1;
  for (int s=0; s<64; s++, t+=dt){
    // phase 1 (wave0): rho_t = act(Wcat @ [h_t; z_t; dz_t] + bcat)
    if (wv == 0){
      HP ht;
      { const uint4* _r=(const uint4*)&sH4[t][0];
        #pragma unroll
        for (int _k=0;_k<8;_k++) ht.q[_k]=_r[_k]; }
      float c0 = bct, c1 = 0.f, c2 = 0.f, c3 = 0.f;
      #pragma unroll
      for (int k=0;k<28;k+=4){
        c0 = fdot2_(wc[k],   hpc(ht,k),   c0);
        c1 = fdot2_(wc[k+1], hpc(ht,k+1), c1);
        c2 = fdot2_(wc[k+2], hpc(ht,k+2), c2);
        c3 = fdot2_(wc[k+3], hpc(ht,k+3), c3);
      }
      c0 = fdot2_(wc[28], hpc(ht,28), c0);
      c1 = fdot2_(wc[29], hpc(ht,29), c1);
      #pragma unroll
      for (int p2=0;p2<5;p2++){
        c2 = fdot2_(wc[30+p2], sZp [t][p2], c2);
        c3 = fdot2_(wc[35+p2], sDZp[t][p2], c3);
      }
      float acc = (c0 + c1) + (c2 + c3);
      float rv = bwd ? acc : tanh_(acc);
      if (u < SP){
        sRhoOut[t][u] = rv;                               // LDS, bulk-store later
        *(f16*)((char*)&sRhoPad[0] + 2*u) = (f16)rv;
      }
      const int slot = bwd ? t : (t - (NN-OO));
      if (slot >= 0 && slot < 8 && u < SP)
        *(f16*)((char*)&sRhoHist[slot][0] + 2*u) = (f16)rv;
    }
    __syncthreads();   // rho stores -> cross-wave fragment reads

    const float blendT = sHas[t];
    const int cnt = sConsCnt[t];
    if (blendT != 0.f && cnt > 0){
      const f16x8 Br0 = bc16(sRhoPad[q]);
      const f16x8 Br1 = bc16(sRhoPad[4+q]);
      f32x4 Gn[2];
      #pragma unroll
      for (int lmt=0;lmt<2;lmt++){
        f32x4 g={0,0,0,0};
        g = mfma16(Ani[lmt][0], Br0, g);
        g = mfma16(Ani[lmt][1], Br1, g);
        Gn[lmt] = g;
      }
      for (int p=0; 16*p < cnt; p++){
        const int idxp = 16*p + ml;
        const int ci = (idxp < cnt) ? (int)sConsL[t][idxp] : 64;
        const f16x8 Bh0 = bc16(sH4[ci][q]);
        const f16x8 Bh1 = bc16(sH4[ci][4+q]);
        gatepass(Bh0, Bh1, Br0, Br1, Gn, ci, idxp < cnt, 1.0f);
      }
    }
    __syncthreads();   // h writes -> next step reads
  }

  // bulk rho store (retires during the alpha tail)
  for (int idx=tid; idx<NN*SP; idx+=128){
    int n2 = idx/SP, s2 = idx%SP;
    rho[((size_t)n2*BATCH + b)*SP + s2] = sRhoOut[n2][s2];
  }

  // ---- alpha tail: 8 GRU steps on scratch row 64 (split across waves) ----
  for (int s2=0; s2<8; s2++){
    const int i = bwd ? (7 - s2) : (NN - OO + s2);
    const int slot = bwd ? i : (i - (NN-OO));
    const f16x8 Th0 = bc16(sH4[64][q]);
    const f16x8 Th1 = bc16(sH4[64][4+q]);
    const f16x8 Tr0 = bc16(sRhoHist[slot][q]);
    const f16x8 Tr1 = bc16(sRhoHist[slot][4+q]);
    f32x4 Gt[2];
    #pragma unroll
    for (int lmt=0;lmt<2;lmt++){
      f32x4 g={0,0,0,0};
      g = mfma16(Ani[lmt][0], Tr0, g);
      g = mfma16(Ani[lmt][1], Tr1, g);
      Gt[lmt] = g;
    }
    gatepass(Th0, Th1, Tr0, Tr1, Gt, 64, ml==0, sHas[i]);
    __syncthreads();
  }
  if (tid < SP) alpha[(size_t)b*SP + tid] = (float)*(const f16*)(ROWB(64) + 2*tid);
  #undef ROWB
}

// One block per batch element: psi + softmaxes, omega, value -> d_out directly.
// r12 head: raw-input reads, wave-level parallel softmax reductions.
__global__ __launch_bounds__(256, 1) void head_kernel(
  const void* __restrict__ hasv,
  const void* __restrict__ Wav, const void* __restrict__ bav,
  const void* __restrict__ Wcv, const void* __restrict__ bcv,
  const void* __restrict__ Wuv, const void* __restrict__ buv,
  const float* __restrict__ ws, void* __restrict__ outp)
{
  const int b = blockIdx.x;
  const int tid = threadIdx.x;
  const int isbf = detect_bf16((const u32*)hasv);
  auto gf = [&](const void* p, int i)->float{
    return isbf ? us2f(((const u16*)p)[i]) : ((const float*)p)[i];
  };
  const float* rhoF   = ws + OFF_RHOF;
  const float* rhoB   = ws + OFF_RHOB;
  const float* alphaF = ws + OFF_ALF;
  const float* alphaB = ws + OFF_ALB;

  __shared__ float sF[NN][121];
  __shared__ float sAB[120];
  __shared__ float sWu[NR*120];
  __shared__ float sHasR[NN];
  __shared__ float sPsi[NR][NN];
  __shared__ float sRed[NR][2];
  __shared__ float sOm[NA];

  auto wout = [&](int idx, float v){
    if (isbf) ((u16*)outp)[idx] = f2bf(v);
    else      ((float*)outp)[idx] = v;
  };

  for (int idx=tid; idx<NN*SP; idx+=256){
    int n = idx/SP, s = idx%SP;
    sF[n][s]    = rhoF[((size_t)n*BATCH + b)*SP + s];
    sF[n][60+s] = rhoB[((size_t)n*BATCH + b)*SP + s];
  }
  for (int idx=tid; idx<120; idx+=256)
    sAB[idx] = (idx<60) ? alphaF[(size_t)b*SP + idx] : alphaB[(size_t)b*SP + idx-60];
  for (int idx=tid; idx<NR*120; idx+=256) sWu[idx] = gf(Wuv, idx);
  for (int idx=tid; idx<NN; idx+=256) sHasR[idx] = gf(hasv, b*NN + idx);
  __syncthreads();

  // psi matrix (448 entries over 256 threads)
  for (int idx=tid; idx<NR*NN; idx+=256){
    int r = idx/NN, n = idx%NN;
    float acc = gf(buv, r);
    for (int s=0;s<120;s++) acc += sF[n][s]*sWu[r*120+s];
    sPsi[r][n] = (sHasR[n] != 0.f) ? acc : -60.f;
  }
  // omega rows (r<5) + value (r==5): 32 lanes per row, shuffle-reduced
  if (tid < 192){
    int r = tid >> 5, j = tid & 31;
    float acc = 0.f;
    if (r < NA){
      for (int s=j; s<120; s+=32) acc += sAB[s]*gf(Wav, r*120+s);
    } else {
      for (int s=j; s<120; s+=32) acc += sAB[s]*gf(Wcv, s);
    }
    for (int off=16; off; off>>=1) acc += __shfl_xor(acc, off, 32);
    if (j == 0){
      if (r < NA) sOm[r] = acc + gf(bav, r);
      else wout(2560 + BATCH*NR*NN + b, acc + gf(bcv, 0));   // value
    }
  }
  __syncthreads();

  // psi row softmax stats: 7 rows x 32 lanes (2 nodes/lane)
  if (tid < 224){
    int r = tid >> 5, j = tid & 31;
    float a = sPsi[r][j], c = sPsi[r][j+32];
    float m = fmaxf(a, c);
    for (int off=16; off; off>>=1) m = fmaxf(m, __shfl_xor(m, off, 32));
    float e = __expf(a-m) + __expf(c-m);
    for (int off=16; off; off>>=1) e += __shfl_xor(e, off, 32);
    if (j == 0){ sRed[r][0] = m; sRed[r][1] = 1.f/e; }
  } else if (tid == 224){
    // omega softmax (5 elements) + instr_prob out
    float m = -1e30f;
    for (int a=0;a<NA;a++) m = fmaxf(m, sOm[a]);
    float e[NA]; float ssum = 0.f;
    for (int a=0;a<NA;a++){ e[a] = __expf(sOm[a]-m); ssum += e[a]; }
    float inv = 1.f/ssum;
    for (int a=0;a<NA;a++) wout(b*NA + a, e[a]*inv);          // instr_prob
  }
  __syncthreads();

  for (int idx=tid; idx<NR*NN; idx+=256){
    int r = idx/NN, n = idx%NN;
    float v = __expf(sPsi[r][n]-sRed[r][0]) * sRed[r][1];
    wout(2560 + (size_t)b*NR*NN + idx, v);                    // role_prob
  }
}

extern "C" void kernel_launch(void* const* d_in, const int* in_sizes, int n_in,
                              void* d_out, int out_size, void* d_ws, size_t ws_size,
                              hipStream_t stream)
{
  const int* adj = (const int*)d_in[3];
  float* ws = (float*)d_ws;

  conv_in<<<(CONV_TOTAL+255)/256, 256, 0, stream>>>(
      d_in[0], d_in[1], d_in[2],
      d_in[4], d_in[5], d_in[6], d_in[7],
      d_in[8], d_in[9], d_in[10], d_in[11],
      d_in[12], d_in[13], d_in[14], d_in[15],
      ws);

  dir_kernel<<<1024, 128, 0, stream>>>(adj, ws);

  head_kernel<<<512, 256, 0, stream>>>(
      d_in[2], d_in[16], d_in[17], d_in[18], d_in[19],
      d_in[20], d_in[21], ws, d_out);
}

// Round 15
// 300.743 us; speedup vs baseline: 1.1125x; 1.1125x over previous
//
#include <hip/hip_runtime.h>
#include <hip/hip_bf16.h>

#define NN 64
#define BATCH 512
#define SP 60
#define SG 180
#define SEX 10
#define CATD 80
#define NA 5
#define NR 7
#define OO 8
#define II 8

typedef unsigned long long u64;
typedef unsigned short u16;
typedef unsigned int u32;
typedef unsigned char u8;

// ---- workspace layout (float offsets) ----
#define OFF_Z     0
#define OFF_DZ    327680
#define OFF_HAS   655360
#define OFF_WIHF  688128
#define OFF_WHHF  698928
#define OFF_BIHF  709728
#define OFF_BHHF  709908
#define OFF_WIHB  710088
#define OFF_WHHB  720888
#define OFF_BIHB  731688
#define OFF_BHHB  731868
#define OFF_WF    732048
#define OFF_BF    736848
#define OFF_WB    736908
#define OFF_BB    741708
#define OFF_WA    741768
#define OFF_BA    742368
#define OFF_WC    742373
#define OFF_BC    742493
#define OFF_WU    742494
#define OFF_BU    743334
#define CONV_TOTAL 743341
#define OFF_FLAG  743342
#define OFF_RHOF  743344
#define OFF_RHOB  (OFF_RHOF + 1966080)
#define OFF_ALF   (OFF_RHOB + 1966080)
#define OFF_ALB   (OFF_ALF + 30720)
#define OUT_TOTAL 232448

typedef _Float16 f16;
typedef _Float16 half2_t __attribute__((ext_vector_type(2)));
typedef _Float16 f16x8 __attribute__((ext_vector_type(8)));
typedef float f32x4 __attribute__((ext_vector_type(4)));

__device__ __forceinline__ float us2f(u16 v){
  return __uint_as_float(((u32)v) << 16);
}
__device__ __forceinline__ u16 f2bf(float f){
  __hip_bfloat16 h = __float2bfloat16(f);
  return *reinterpret_cast<u16*>(&h);
}
__device__ __forceinline__ float rcp_(float x){ return __builtin_amdgcn_rcpf(x); }
__device__ __forceinline__ float sigm(float x){
  return rcp_(1.f + __expf(-x));
}
__device__ __forceinline__ float tanh_(float x){
  float e = __expf(2.f*fabsf(x));
  float t = 1.f - 2.f*rcp_(e + 1.f);
  return copysignf(t, x);
}
__device__ __forceinline__ u32 pack2(float a, float b){
  half2_t h; h[0] = (f16)a; h[1] = (f16)b;
  return __builtin_bit_cast(u32, h);
}
__device__ __forceinline__ float fdot2_(u32 a, u32 b, float c){
  return __builtin_amdgcn_fdot2(__builtin_bit_cast(half2_t, a),
                                __builtin_bit_cast(half2_t, b), c, false);
}
__device__ __forceinline__ f16x8 bc16(uint4 v){ return __builtin_bit_cast(f16x8, v); }
__device__ __forceinline__ f32x4 mfma16(f16x8 a, f16x8 b, f32x4 c){
  return __builtin_amdgcn_mfma_f32_16x16x32_f16(a, b, c, 0, 0, 0);
}

struct HP { uint4 q[8]; };
__device__ __forceinline__ u32 hpc(const HP& p, int k){
  const uint4& v = p.q[k>>2];
  switch(k&3){ case 0: return v.x; case 1: return v.y; case 2: return v.z; default: return v.w; }
}

// has is exactly {0,1}. f32 words: only 0x00000000 / 0x3F800000.
// bf16-pair words: 0x3F803F80 == (1.0,1.0) appears w.p. ~0.81 per pair.
__device__ __forceinline__ int detect_bf16(const u32* w){
  int f = 0;
  for (int i=0;i<256;i++) f |= (w[i] == 0x3F803F80u) ? 1 : 0;
  return f;
}

__global__ __launch_bounds__(256) void conv_in(
  const void* z, const void* dz, const void* has,
  const void* WihF, const void* WhhF, const void* bihF, const void* bhhF,
  const void* WihB, const void* WhhB, const void* bihB, const void* bhhB,
  const void* Wf_, const void* bf_, const void* Wb_, const void* bb_,
  const void* Wa, const void* ba, const void* Wc, const void* bc,
  const void* Wu, const void* bu, float* ws)
{
  const int isbf = detect_bf16((const u32*)has);
  if (blockIdx.x == 0 && threadIdx.x == 0) ws[OFF_FLAG] = (float)isbf;
  int idx = blockIdx.x*256 + threadIdx.x;
  if (idx >= CONV_TOTAL) return;
  const void* src; int loc;
  if      (idx < OFF_DZ  ){ src=z;    loc=idx-OFF_Z;    }
  else if (idx < OFF_HAS ){ src=dz;   loc=idx-OFF_DZ;   }
  else if (idx < OFF_WIHF){ src=has;  loc=idx-OFF_HAS;  }
  else if (idx < OFF_WHHF){ src=WihF; loc=idx-OFF_WIHF; }
  else if (idx < OFF_BIHF){ src=WhhF; loc=idx-OFF_WHHF; }
  else if (idx < OFF_BHHF){ src=bihF; loc=idx-OFF_BIHF; }
  else if (idx < OFF_WIHB){ src=bhhF; loc=idx-OFF_BHHF; }
  else if (idx < OFF_WHHB){ src=WihB; loc=idx-OFF_WIHB; }
  else if (idx < OFF_BIHB){ src=WhhB; loc=idx-OFF_WHHB; }
  else if (idx < OFF_BHHB){ src=bihB; loc=idx-OFF_BIHB; }
  else if (idx < OFF_WF  ){ src=bhhB; loc=idx-OFF_BHHB; }
  else if (idx < OFF_BF  ){ src=Wf_;  loc=idx-OFF_WF;   }
  else if (idx < OFF_WB  ){ src=bf_;  loc=idx-OFF_BF;   }
  else if (idx < OFF_BB  ){ src=Wb_;  loc=idx-OFF_WB;   }
  else if (idx < OFF_WA  ){ src=bb_;  loc=idx-OFF_BB;   }
  else if (idx < OFF_BA  ){ src=Wa;   loc=idx-OFF_WA;   }
  else if (idx < OFF_WC  ){ src=ba;   loc=idx-OFF_BA;   }
  else if (idx < OFF_BC  ){ src=Wc;   loc=idx-OFF_WC;   }
  else if (idx < OFF_WU  ){ src=bc;   loc=idx-OFF_BC;   }
  else if (idx < OFF_BU  ){ src=Wu;   loc=idx-OFF_WU;   }
  else                    { src=bu;   loc=idx-OFF_BU;   }
  float v = isbf ? us2f(((const u16*)src)[loc]) : ((const float*)src)[loc];
  ws[idx] = v;
}

// Pipelined DAG-GRU, MFMA with in-register gates (r11 configuration —
// session-best: dir 186 us, total 303 us).
__global__ __launch_bounds__(64, 1) void dir_kernel(const int* __restrict__ adj,
                                                    float* __restrict__ ws)
{
  const int u   = threadIdx.x;      // lane
  const int ml  = u & 15;           // MFMA col (consumer slot)
  const int q   = u >> 4;           // MFMA quad
  const int bid = blockIdx.x;
  const int bwd = bid >> 9;
  const int b   = bid & 511;

  const float* Wih  = ws + (bwd ? OFF_WIHB : OFF_WIHF);
  const float* Whh  = ws + (bwd ? OFF_WHHB : OFF_WHHF);
  const float* bih  = ws + (bwd ? OFF_BIHB : OFF_BIHF);
  const float* bhh  = ws + (bwd ? OFF_BHHB : OFF_BHHF);
  const float* Wcat = ws + (bwd ? OFF_WB   : OFF_WF);
  const float* bcat = ws + (bwd ? OFF_BB   : OFF_BF);
  const float* zc   = ws + OFF_Z;
  const float* dzc  = ws + OFF_DZ;
  const float* hasc = ws + OFF_HAS;
  float* rho   = ws + (bwd ? OFF_RHOB : OFF_RHOF);  // [64][512][60]
  float* alpha = ws + (bwd ? OFF_ALB  : OFF_ALF);   // [512][60]

  __shared__ uint4 sH4[65][9];        // h rows, 144B stride; half63=1.0 (bias ch)
  __shared__ uint4 sRhoPad[8];        // rho_t halves; half63=1.0
  __shared__ uint4 sRhoHist[8][8];    // tail rho history; half63=1.0
  __shared__ float sRhoOut[NN][SP];   // f32 rho staging (bulk global write)
  __shared__ u32 sZp[NN][5];
  __shared__ u32 sDZp[NN][5];
  __shared__ float sHas[NN];
  __shared__ u64 sRowM[NN];
  __shared__ u8 sConsL[NN][64];       // consumer lists (batch-independent)
  __shared__ int sConsCnt[NN];

  #define ROWB(I) ((char*)&sH4[(I)][0])
  const u32 BIASW = 0x3C000000u;      // halves {0, 1.0h}

  // ---- staging ----
  u64 rowm = 0;
  {
    for (int j=0;j<64;j++) rowm |= ((u64)(adj[u*64+j]!=0))<<j;
    sRowM[u] = rowm;
    sHas[u] = hasc[b*NN + u];
    for (int idx=u; idx<65*9; idx+=64){
      uint4 v = {0,0,0,0};
      if (idx % 9 == 7) v.w = BIASW;         // half63 = 1.0
      ((uint4*)sH4)[idx] = v;
    }
    if (u < 8){ uint4 v={0,0,0,0}; if (u==7) v.w = BIASW; sRhoPad[u]=v; }
    { uint4 v={0,0,0,0}; if ((u&7)==7) v.w = BIASW; ((uint4*)sRhoHist)[u]=v; }
    for (int idx=u; idx<NN*5; idx+=64){
      int n2=idx/5, p2=idx%5;
      sZp [n2][p2] = pack2(zc [(size_t)b*NN*SEX + n2*SEX + 2*p2],
                           zc [(size_t)b*NN*SEX + n2*SEX + 2*p2+1]);
      sDZp[n2][p2] = pack2(dzc[(size_t)b*NN*SEX + n2*SEX + 2*p2],
                           dzc[(size_t)b*NN*SEX + n2*SEX + 2*p2+1]);
    }
  }
  __syncthreads();
  {
    u64 cm = 0;
    if (bwd) for (int i2=0;i2<64;i2++) cm |= ((sRowM[i2]>>u)&1ULL)<<i2;
    u64 m = bwd ? cm : rowm;                // consumers of node u
    int c = 0;
    while (m){ int i2 = (int)__builtin_ctzll(m); m &= m-1; sConsL[u][c++] = (u8)i2; }
    sConsCnt[u] = c;
  }

  // ---- A fragments: lane (q,ml) holds A[row=16mt+ml][K=32kt+8q+j] ----
  // Ar/Az: K<60 Whh, 64<=K<124 Wih, K==127 bias (bhh+bih). 64 rows (60 used).
  // Anh:   K<60 Whh_n, K==63 bias bhh_n.   Ani: K<60 Wih_n, K==63 bias bih_n.
  f16x8 Ar[4][4], Az[4][4], Anh[4][2], Ani[4][2];
  #pragma unroll
  for (int mt=0; mt<4; mt++){
    const int R = 16*mt + ml;
    const bool rok = (R < SP);
    #pragma unroll
    for (int kt=0; kt<4; kt++){
      f16x8 vr, vz;
      #pragma unroll
      for (int j=0;j<8;j++){
        const int K = 32*kt + 8*q + j;
        float wr=0.f, wz=0.f;
        if (rok){
          if (K < SP){ wr = Whh[R*SP+K]; wz = Whh[(60+R)*SP+K]; }
          else if (K >= 64 && K < 64+SP){ wr = Wih[R*SP+(K-64)]; wz = Wih[(60+R)*SP+(K-64)]; }
          else if (K == 127){ wr = bhh[R]+bih[R]; wz = bhh[60+R]+bih[60+R]; }
        }
        vr[j]=(f16)wr; vz[j]=(f16)wz;
      }
      Ar[mt][kt]=vr; Az[mt][kt]=vz;
    }
    #pragma unroll
    for (int kt=0; kt<2; kt++){
      f16x8 vn, vi;
      #pragma unroll
      for (int j=0;j<8;j++){
        const int K = 32*kt + 8*q + j;
        float wn=0.f, wi=0.f;
        if (rok){
          if (K < SP){ wn = Whh[(120+R)*SP+K]; wi = Wih[(120+R)*SP+K]; }
          else if (K == 63){ wn = bhh[120+R]; wi = bih[120+R]; }
        }
        vn[j]=(f16)wn; vi[j]=(f16)wi;
      }
      Anh[mt][kt]=vn; Ani[mt][kt]=vi;
    }
  }

  // rho weights (packed f16 pairs) + bias
  u32 wc[40];
  #pragma unroll
  for (int k=0;k<40;k++) wc[k] = pack2(Wcat[u*CATD + 2*k], Wcat[u*CATD + 2*k+1]);
  const float bct = bcat[u];
  __syncthreads();   // lists + LDS init visible

  // gate pass: GEMMs + in-register gates + h update for row set {ci per ml}
  auto gatepass = [&](f16x8 Bh0, f16x8 Bh1, f16x8 Br0, f16x8 Br1,
                      const f32x4* Gn, int ci, bool wr, float bl){
    f32x4 Dr[4], Dz[4], Dn[4];
    #pragma unroll
    for (int mt=0;mt<4;mt++){
      f32x4 a={0,0,0,0};
      a = mfma16(Ar[mt][0], Bh0, a); a = mfma16(Ar[mt][1], Bh1, a);
      a = mfma16(Ar[mt][2], Br0, a); a = mfma16(Ar[mt][3], Br1, a);
      Dr[mt] = a;
      f32x4 c2={0,0,0,0};
      c2 = mfma16(Az[mt][0], Bh0, c2); c2 = mfma16(Az[mt][1], Bh1, c2);
      c2 = mfma16(Az[mt][2], Br0, c2); c2 = mfma16(Az[mt][3], Br1, c2);
      Dz[mt] = c2;
      f32x4 d={0,0,0,0};
      d = mfma16(Anh[mt][0], Bh0, d); d = mfma16(Anh[mt][1], Bh1, d);
      Dn[mt] = d;
    }
    #pragma unroll
    for (int mt=0;mt<4;mt++){
      char* rp = ROWB(ci) + 32*mt + 8*q;
      uint2 h2 = *(uint2*)rp;
      half2_t ha = __builtin_bit_cast(half2_t, h2.x);
      half2_t hb = __builtin_bit_cast(half2_t, h2.y);
      float hold[4] = { (float)ha[0], (float)ha[1], (float)hb[0], (float)hb[1] };
      float hw[4];
      #pragma unroll
      for (int reg=0;reg<4;reg++){
        float r_ = sigm(Dr[mt][reg]);
        float zg = sigm(Dz[mt][reg]);
        float nv = tanh_(Gn[mt][reg] + r_*Dn[mt][reg]);
        float hn_ = (1.f - zg)*nv + zg*hold[reg];
        hw[reg] = (bl != 0.f) ? hn_ : hold[reg];   // bl is exactly 0 or 1
      }
      if (wr && !(mt==3 && q==3)){
        uint2 o; o.x = pack2(hw[0],hw[1]); o.y = pack2(hw[2],hw[3]);
        *(uint2*)rp = o;
      }
    }
  };

  // ---- 64 pipelined steps ----
  int t = bwd ? 63 : 0;
  const int dt = bwd ? -1 : 1;
  for (int s=0; s<64; s++, t+=dt){
    // phase 1: rho_t = act(Wcat @ [h_t; z_t; dz_t] + bcat)  (4 fdot2 chains)
    {
      HP ht;
      { const uint4* _r=(const uint4*)&sH4[t][0];
        #pragma unroll
        for (int _k=0;_k<8;_k++) ht.q[_k]=_r[_k]; }
      float c0 = bct, c1 = 0.f, c2 = 0.f, c3 = 0.f;
      #pragma unroll
      for (int k=0;k<28;k+=4){
        c0 = fdot2_(wc[k],   hpc(ht,k),   c0);
        c1 = fdot2_(wc[k+1], hpc(ht,k+1), c1);
        c2 = fdot2_(wc[k+2], hpc(ht,k+2), c2);
        c3 = fdot2_(wc[k+3], hpc(ht,k+3), c3);
      }
      c0 = fdot2_(wc[28], hpc(ht,28), c0);
      c1 = fdot2_(wc[29], hpc(ht,29), c1);
      #pragma unroll
      for (int p2=0;p2<5;p2++){
        c2 = fdot2_(wc[30+p2], sZp [t][p2], c2);
        c3 = fdot2_(wc[35+p2], sDZp[t][p2], c3);
      }
      float acc = (c0 + c1) + (c2 + c3);
      float rv = bwd ? acc : tanh_(acc);
      if (u < SP){
        sRhoOut[t][u] = rv;                               // LDS, bulk-store later
        *(f16*)((char*)&sRhoPad[0] + 2*u) = (f16)rv;
      }
      const int slot = bwd ? t : (t - (NN-OO));
      if (slot >= 0 && slot < 8 && u < SP)
        *(f16*)((char*)&sRhoHist[slot][0] + 2*u) = (f16)rv;
    }
    __syncthreads();   // rho stores -> cross-lane fragment reads (lgkm only)

    const float blendT = sHas[t];
    const int cnt = sConsCnt[t];
    if (blendT != 0.f && cnt > 0){
      const f16x8 Br0 = bc16(sRhoPad[q]);
      const f16x8 Br1 = bc16(sRhoPad[4+q]);
      f32x4 Gn[4];
      #pragma unroll
      for (int mt=0;mt<4;mt++){
        f32x4 g={0,0,0,0};
        g = mfma16(Ani[mt][0], Br0, g);
        g = mfma16(Ani[mt][1], Br1, g);
        Gn[mt] = g;
      }
      for (int p=0; 16*p < cnt; p++){
        const int idxp = 16*p + ml;
        const int ci = (idxp < cnt) ? (int)sConsL[t][idxp] : 64;
        const f16x8 Bh0 = bc16(sH4[ci][q]);
        const f16x8 Bh1 = bc16(sH4[ci][4+q]);
        gatepass(Bh0, Bh1, Br0, Br1, Gn, ci, idxp < cnt, 1.0f);
      }
    }
    __syncthreads();   // h writes -> next step reads
  }

  // bulk rho store (retires during the alpha tail)
  for (int idx=u; idx<NN*SP; idx+=64){
    int n2 = idx/SP, s2 = idx%SP;
    rho[((size_t)n2*BATCH + b)*SP + s2] = sRhoOut[n2][s2];
  }

  // ---- alpha tail: 8 GRU steps on scratch row 64 ----
  for (int s2=0; s2<8; s2++){
    const int i = bwd ? (7 - s2) : (NN - OO + s2);
    const int slot = bwd ? i : (i - (NN-OO));
    const f16x8 Th0 = bc16(sH4[64][q]);
    const f16x8 Th1 = bc16(sH4[64][4+q]);
    const f16x8 Tr0 = bc16(sRhoHist[slot][q]);
    const f16x8 Tr1 = bc16(sRhoHist[slot][4+q]);
    f32x4 Gt[4];
    #pragma unroll
    for (int mt=0;mt<4;mt++){
      f32x4 g={0,0,0,0};
      g = mfma16(Ani[mt][0], Tr0, g);
      g = mfma16(Ani[mt][1], Tr1, g);
      Gt[mt] = g;
    }
    gatepass(Th0, Th1, Tr0, Tr1, Gt, 64, ml==0, sHas[i]);
    __syncthreads();
  }
  if (u < SP) alpha[(size_t)b*SP + u] = (float)*(const f16*)(ROWB(64) + 2*u);
  #undef ROWB
}

// One block per batch element: psi + softmaxes, omega, value -> d_out directly.
__global__ __launch_bounds__(256, 1) void head_kernel(float* __restrict__ ws,
                                                      void* __restrict__ outp)
{
  const int b = blockIdx.x;
  const int tid = threadIdx.x;
  const int isbf = (ws[OFF_FLAG] != 0.f);
  const float* hasc   = ws + OFF_HAS;
  const float* WaC    = ws + OFF_WA;
  const float* baC    = ws + OFF_BA;
  const float* WcC    = ws + OFF_WC;
  const float* bcC    = ws + OFF_BC;
  const float* WuC    = ws + OFF_WU;
  const float* buC    = ws + OFF_BU;
  const float* rhoF   = ws + OFF_RHOF;
  const float* rhoB   = ws + OFF_RHOB;
  const float* alphaF = ws + OFF_ALF;
  const float* alphaB = ws + OFF_ALB;

  __shared__ float sF[NN][121];
  __shared__ float sAB[120];
  __shared__ float sWu[NR*120];
  __shared__ float sHasR[NN];
  __shared__ float sPsi[NR][NN];
  __shared__ float sRed[NR][2];
  __shared__ float sOm[NA];

  auto wout = [&](int idx, float v){
    if (isbf) ((u16*)outp)[idx] = f2bf(v);
    else      ((float*)outp)[idx] = v;
  };

  for (int idx=tid; idx<NN*SP; idx+=256){
    int n = idx/SP, s = idx%SP;
    sF[n][s]    = rhoF[((size_t)n*BATCH + b)*SP + s];
    sF[n][60+s] = rhoB[((size_t)n*BATCH + b)*SP + s];
  }
  for (int idx=tid; idx<120; idx+=256)
    sAB[idx] = (idx<60) ? alphaF[(size_t)b*SP + idx] : alphaB[(size_t)b*SP + idx-60];
  for (int idx=tid; idx<NR*120; idx+=256) sWu[idx] = WuC[idx];
  for (int idx=tid; idx<NN; idx+=256) sHasR[idx] = hasc[b*NN + idx];
  __syncthreads();

  for (int idx=tid; idx<NR*NN; idx+=256){
    int r = idx/NN, n = idx%NN;
    float acc = buC[r];
    for (int s=0;s<120;s++) acc += sF[n][s]*sWu[r*120+s];
    sPsi[r][n] = (sHasR[n] != 0.f) ? acc : -60.f;
  }
  if (tid >= 64 && tid < 64+NA){
    int a = tid - 64;
    float acc = baC[a];
    for (int s=0;s<120;s++) acc += sAB[s]*WaC[a*120+s];
    sOm[a] = acc;
  }
  if (tid == 70){
    float acc = bcC[0];
    for (int s=0;s<120;s++) acc += sAB[s]*WcC[s];
    wout(2560 + BATCH*NR*NN + b, acc);                 // value
  }
  __syncthreads();

  if (tid < NR){
    float m = -1e30f;
    for (int n=0;n<NN;n++) m = fmaxf(m, sPsi[tid][n]);
    float ssum = 0.f;
    for (int n=0;n<NN;n++) ssum += __expf(sPsi[tid][n]-m);
    sRed[tid][0] = m; sRed[tid][1] = 1.f/ssum;
  }
  if (tid == 8){
    float m = -1e30f;
    for (int a=0;a<NA;a++) m = fmaxf(m, sOm[a]);
    float e[NA]; float ssum = 0.f;
    for (int a=0;a<NA;a++){ e[a] = __expf(sOm[a]-m); ssum += e[a]; }
    for (int a=0;a<NA;a++) wout(b*NA + a, e[a]/ssum);  // instr_prob
  }
  __syncthreads();

  for (int idx=tid; idx<NR*NN; idx+=256){
    int r = idx/NN, n = idx%NN;
    float v = __expf(sPsi[r][n]-sRed[r][0]) * sRed[r][1];
    wout(2560 + (size_t)b*NR*NN + idx, v);             // role_prob
  }
}

extern "C" void kernel_launch(void* const* d_in, const int* in_sizes, int n_in,
                              void* d_out, int out_size, void* d_ws, size_t ws_size,
                              hipStream_t stream)
{
  const int* adj = (const int*)d_in[3];
  float* ws = (float*)d_ws;

  conv_in<<<(CONV_TOTAL+255)/256, 256, 0, stream>>>(
      d_in[0], d_in[1], d_in[2],
      d_in[4], d_in[5], d_in[6], d_in[7],
      d_in[8], d_in[9], d_in[10], d_in[11],
      d_in[12], d_in[13], d_in[14], d_in[15],
      d_in[16], d_in[17], d_in[18], d_in[19],
      d_in[20], d_in[21], ws);

  dir_kernel<<<1024, 64, 0, stream>>>(adj, ws);

  head_kernel<<<512, 256, 0, stream>>>(ws, d_out);
}